// Round 3
// baseline (269.296 us; speedup 1.0000x reference)
//
#include <hip/hip_runtime.h>

// PhysicsPriorGenerator, two-phase + zero-skip:
//   A: per column (prior,b,a): dt = d/cos((th+ang)*pi/180), inv = valid ? 1/sum_j exp2(K*diff^2) : 0
//      + per-batch row window [jlo,jhi] = rows within 2.6 depth units of any valid dt
//   B: rows in window: out = exp2(K*(dep-dt)^2)*inv ; rows outside: out = 0 (true value < 1.4e-6)
// Output 2x256x512x256 fp32 = 268 MB -> store-roofline ~41 us @ 6.6 TB/s (measured fill rate).

#define DD 512
#define AA 256
#define K2 (-2.8853900817779268f)        // -1/(2*sigma^2)*2*log2(e), sigma=0.5
#define DSTEP (50.0f / 511.0f)
#define ASTEP (60.0f / 255.0f)
#define CUT 2.6f

// ---- Kernel A: block = pb (0..511), thread = angle. ws: float2 {dt,inv} per col; win: int2 per pb ----
__global__ __launch_bounds__(256) void prior_setup(const float* __restrict__ p0,
                                                   const float* __restrict__ p1,
                                                   float2* __restrict__ ws,
                                                   int2* __restrict__ win) {
    const int pb = blockIdx.x;
    const int a  = threadIdx.x;
    const float* __restrict__ pp = (pb < 256) ? (p0 + 3 * pb) : (p1 + 3 * (pb - 256));
    const float d  = pp[1];
    const float th = pp[2];

    const float ang = -30.0f + (float)a * ASTEP;
    const float rad = (th + ang) * 0.017453292519943295f;
    const float dt  = d / cosf(rad);
    const bool valid = (dt > 0.0f) && (dt < 50.0f);

    float s0 = 0.0f, s1 = 0.0f, s2 = 0.0f, s3 = 0.0f;
    #pragma unroll 4
    for (int j = 0; j < DD; j += 4) {
        float x0 = (float)(j + 0) * DSTEP - dt;
        float x1 = (float)(j + 1) * DSTEP - dt;
        float x2 = (float)(j + 2) * DSTEP - dt;
        float x3 = (float)(j + 3) * DSTEP - dt;
        s0 += __builtin_amdgcn_exp2f(K2 * x0 * x0);
        s1 += __builtin_amdgcn_exp2f(K2 * x1 * x1);
        s2 += __builtin_amdgcn_exp2f(K2 * x2 * x2);
        s3 += __builtin_amdgcn_exp2f(K2 * x3 * x3);
    }
    const float sum = (s0 + s1) + (s2 + s3);
    const float den = (sum > 0.0f) ? sum : 1.0f;
    float2 r;
    r.x = valid ? dt : 1.0e9f;
    r.y = valid ? (1.0f / den) : 0.0f;
    ws[pb * AA + a] = r;

    // min/max valid dt -> row window for kernel B
    float vmin = valid ? dt : 1.0e30f;
    float vmax = valid ? dt : -1.0e30f;
    #pragma unroll
    for (int off = 32; off >= 1; off >>= 1) {
        vmin = fminf(vmin, __shfl_xor(vmin, off, 64));
        vmax = fmaxf(vmax, __shfl_xor(vmax, off, 64));
    }
    __shared__ float smin[4], smax[4];
    if ((a & 63) == 0) { smin[a >> 6] = vmin; smax[a >> 6] = vmax; }
    __syncthreads();
    if (a == 0) {
        float m0 = fminf(fminf(smin[0], smin[1]), fminf(smin[2], smin[3]));
        float m1 = fmaxf(fmaxf(smax[0], smax[1]), fmaxf(smax[2], smax[3]));
        int2 w;
        if (m1 < m0) { w.x = 1; w.y = 0; }               // no valid column -> all zeros
        else {
            w.x = max(0,      (int)ceilf ((m0 - CUT) / DSTEP));
            w.y = min(DD - 1, (int)floorf((m1 + CUT) / DSTEP));
        }
        win[pb] = w;
    }
}

// ---- Kernel B: block = (pb, chunk of 64 rows); wave-uniform zero-skip outside window ----
__global__ __launch_bounds__(256) void prior_write(const float4* __restrict__ ws,
                                                   const int2* __restrict__ win,
                                                   float* __restrict__ out) {
    const int gid   = blockIdx.x;
    const int pb    = gid >> 3;
    const int chunk = gid & 7;
    const int t     = threadIdx.x;
    const int a4    = (t & 63) * 4;
    const int jb    = t >> 6;

    const int2 w = win[pb];                 // uniform per block
    const float4 e0 = ws[pb * 128 + (t & 63) * 2];      // {dt0,inv0,dt1,inv1}
    const float4 e1 = ws[pb * 128 + (t & 63) * 2 + 1];  // {dt2,inv2,dt3,inv3}

    float* __restrict__ outp = out + (size_t)pb * (DD * AA) + a4;
    const int j0 = chunk * 64 + jb * 16;
    const float4 z = make_float4(0.0f, 0.0f, 0.0f, 0.0f);
    #pragma unroll
    for (int i = 0; i < 16; ++i) {
        const int j = j0 + i;               // uniform within wave
        if (j < w.x || j > w.y) {
            *(float4*)(outp + (size_t)j * AA) = z;
        } else {
            const float dep = (float)j * DSTEP;
            float4 v;
            float dx = dep - e0.x; v.x = __builtin_amdgcn_exp2f(K2 * dx * dx) * e0.y;
            float dy = dep - e0.z; v.y = __builtin_amdgcn_exp2f(K2 * dy * dy) * e0.w;
            float dz = dep - e1.x; v.z = __builtin_amdgcn_exp2f(K2 * dz * dz) * e1.y;
            float dw = dep - e1.z; v.w = __builtin_amdgcn_exp2f(K2 * dw * dw) * e1.w;
            *(float4*)(outp + (size_t)j * AA) = v;
        }
    }
}

extern "C" void kernel_launch(void* const* d_in, const int* in_sizes, int n_in,
                              void* d_out, int out_size, void* d_ws, size_t ws_size,
                              hipStream_t stream) {
    const float* p0 = (const float*)d_in[0];   // p        (256 x 3)
    const float* p1 = (const float*)d_in[1];   // p_calib  (256 x 3)
    float* out = (float*)d_out;                // 2 x 256 x 512 x 256 fp32
    float2* ws = (float2*)d_ws;                // 131072 x {dt,inv} = 1 MB
    int2* win  = (int2*)((char*)d_ws + (size_t)2 * 256 * AA * sizeof(float2)); // +512*8B

    prior_setup<<<dim3(512), dim3(256), 0, stream>>>(p0, p1, ws, win);
    prior_write<<<dim3(512 * 8), dim3(256), 0, stream>>>((const float4*)ws, win, out);
}